// Round 1
// baseline (176.035 us; speedup 1.0000x reference)
//
#include <hip/hip_runtime.h>
#include <hip/hip_bf16.h>

typedef __attribute__((ext_vector_type(4))) float f32x4;
typedef __attribute__((ext_vector_type(8))) short s16x8;

// ---------------------------------------------------------------------------
// k0: pack g_fc2_w (64,256,256) fp32 -> bf16, pre-swizzled so that each
// (n, kt64) K-tile is the exact byte image k2 wants in LDS.
// chunk ci = c*8 + s, s = kc ^ (c&7); chunk holds W[n][kt*64+kc*8+j][c], j=0..7
// ---------------------------------------------------------------------------
__global__ __launch_bounds__(256) void k0_pack(const float* __restrict__ w2,
                                               ushort* __restrict__ out) {
  int tid = blockIdx.x * 256 + threadIdx.x;   // 524288 total
  int ci = tid & 2047;
  int nt = tid >> 11;                         // n*4 + kt
  int c  = ci >> 3;
  int s  = ci & 7;
  int kc = s ^ (c & 7);
  int n  = nt >> 2;
  int kt = nt & 3;
  const float* src = w2 + ((size_t)n * 256 + (kt * 64 + kc * 8)) * 256 + c;
  s16x8 pk;
#pragma unroll
  for (int j = 0; j < 8; ++j) {
    __hip_bfloat16 h = __float2bfloat16(src[(size_t)j * 256]);
    pk[j] = *reinterpret_cast<short*>(&h);
  }
  *reinterpret_cast<s16x8*>(out + (size_t)tid * 8) = pk;
}

// ---------------------------------------------------------------------------
// k1: f-path -> sparse_w (4096,64).  16 rows per block, 256 threads.
// ---------------------------------------------------------------------------
__global__ __launch_bounds__(256) void k1_select(
    const float* __restrict__ x,
    const float* __restrict__ w1, const float* __restrict__ b1,
    const float* __restrict__ w2, const float* __restrict__ b2,
    const float* __restrict__ wsk, const float* __restrict__ bsk,
    const float* __restrict__ wg, const float* __restrict__ bg,
    const float* __restrict__ lng, const float* __restrict__ lnb,
    float* __restrict__ spw) {
  __shared__ float xs[16][64];
  __shared__ float t1[16][256];
  __shared__ float wvv[16][64];
  const int t = threadIdx.x;
  const int b0 = blockIdx.x * 16;
  {
    const f32x4* xin = reinterpret_cast<const f32x4*>(x + (size_t)b0 * 64);
    reinterpret_cast<f32x4*>(&xs[0][0])[t] = xin[t];
  }
  __syncthreads();
  {  // t1[r][h] = elu(x @ f_fc1_w + b1), thread t = h
    float acc[16];
    float bias = b1[t];
#pragma unroll
    for (int r = 0; r < 16; ++r) acc[r] = bias;
    for (int n = 0; n < 64; ++n) {
      float w = w1[n * 256 + t];
#pragma unroll
      for (int r = 0; r < 16; ++r) acc[r] = fmaf(xs[r][n], w, acc[r]);
    }
#pragma unroll
    for (int r = 0; r < 16; ++r) {
      float z = acc[r];
      t1[r][t] = fmaxf(z, 0.f) + (__expf(fminf(z, 0.f)) - 1.f);
    }
  }
  __syncthreads();
  {  // h2 / skip / gate, thread = (nn = t&63, row-group rg = t>>6)
    const int nn = t & 63, rg = t >> 6;
    float a2[4], as_[4], ag[4];
    float bb2 = b2[nn], bbs = bsk[nn], bbg = bg[nn];
#pragma unroll
    for (int i = 0; i < 4; ++i) { a2[i] = bb2; as_[i] = bbs; ag[i] = bbg; }
    for (int h = 0; h < 256; ++h) {
      float w = w2[h * 64 + nn];
#pragma unroll
      for (int i = 0; i < 4; ++i) a2[i] = fmaf(t1[rg + 4 * i][h], w, a2[i]);
    }
    for (int m = 0; m < 64; ++m) {
      float ws_ = wsk[m * 64 + nn], wg_ = wg[m * 64 + nn];
#pragma unroll
      for (int i = 0; i < 4; ++i) {
        float xv = xs[rg + 4 * i][m];
        as_[i] = fmaf(xv, ws_, as_[i]);
        ag[i]  = fmaf(xv, wg_, ag[i]);
      }
    }
#pragma unroll
    for (int i = 0; i < 4; ++i) {
      float gt = __fdividef(1.f, 1.f + __expf(-ag[i]));
      wvv[rg + 4 * i][nn] = fmaf(gt, a2[i] - as_[i], as_[i]);
    }
  }
  __syncthreads();
  {  // LN over 64 + softmax over 64, wave handles 4 rows
    const int lane = t & 63, wid = t >> 6;
    float gl = lng[lane], bl = lnb[lane];
#pragma unroll
    for (int rr = 0; rr < 4; ++rr) {
      int r = wid * 4 + rr;
      float v = wvv[r][lane];
      float s = v;
      for (int m = 1; m < 64; m <<= 1) s += __shfl_xor(s, m);
      float mu = s * (1.f / 64.f);
      float d = v - mu;
      float q = d * d;
      for (int m = 1; m < 64; m <<= 1) q += __shfl_xor(q, m);
      float wn = d * rsqrtf(q * (1.f / 64.f) + 1e-5f) * gl + bl;
      float mx = wn;
      for (int m = 1; m < 64; m <<= 1) mx = fmaxf(mx, __shfl_xor(mx, m));
      float e = __expf(wn - mx);
      float se = e;
      for (int m = 1; m < 64; m <<= 1) se += __shfl_xor(se, m);
      spw[(size_t)(b0 + r) * 64 + lane] = __fdividef(e, se);
    }
  }
}

// ---------------------------------------------------------------------------
// k2: fused einsum + gate/skip + LN(H) + weighted accumulate.
// grid 512: bid = btile*8 + nchunk  (nchunk = bid&7 -> XCD-pinned weights)
// block 256 thr / 4 waves, BM=64 rows, 8 n per block, col-split waves.
// ---------------------------------------------------------------------------
__global__ __launch_bounds__(256, 2) void k2_main(
    const float* __restrict__ x,
    const ushort* __restrict__ w2p,
    const float* __restrict__ fc1w, const float* __restrict__ fc1b,
    const float* __restrict__ fc2b,
    const float* __restrict__ skw, const float* __restrict__ skb,
    const float* __restrict__ gww, const float* __restrict__ gwb,
    const float* __restrict__ lng, const float* __restrict__ lnb,
    const float* __restrict__ spw,
    float* __restrict__ comb) {
  __shared__ __align__(16) char Ab[32768];   // A tile 64x256 bf16, swizzled
  __shared__ __align__(16) char Bb[32768];   // B K-tile 64x256 bf16, swizzled
  __shared__ float xs[64][8];
  __shared__ float ss[64][8];
  __shared__ float sums[64][2];

  const int bid = blockIdx.x;
  const int nch = bid & 7;
  const int b0  = (bid >> 3) * 64;
  const int t = threadIdx.x;
  const int lane = t & 63;
  const int w = t >> 6;
  const int g = lane >> 4;
  const int cl = lane & 15;

  for (int i = t; i < 512; i += 256) {
    int r = i >> 3, j = i & 7;
    xs[r][j] = x[(size_t)(b0 + r) * 64 + nch * 8 + j];
    ss[r][j] = spw[(size_t)(b0 + r) * 64 + nch * 8 + j];
  }

  f32x4 comb_acc[4][4];
#pragma unroll
  for (int a = 0; a < 4; ++a)
#pragma unroll
    for (int b = 0; b < 4; ++b) comb_acc[a][b] = (f32x4){0.f, 0.f, 0.f, 0.f};

  __syncthreads();

  for (int ni = 0; ni < 8; ++ni) {
    const int n = nch * 8 + ni;
    if (t < 128) (&sums[0][0])[t] = 0.f;
    // ---- A generation: A[r][k] = elu(x[b0+r][n]*fc1w[n][k] + fc1b[n][k]) ----
    {
      const int kc = t & 31;
      const int rb = t >> 5;
      const float* w1p = fc1w + n * 256 + kc * 8;
      const float* b1p = fc1b + n * 256 + kc * 8;
      f32x4 wlo = *reinterpret_cast<const f32x4*>(w1p);
      f32x4 whi = *reinterpret_cast<const f32x4*>(w1p + 4);
      f32x4 blo = *reinterpret_cast<const f32x4*>(b1p);
      f32x4 bhi = *reinterpret_cast<const f32x4*>(b1p + 4);
#pragma unroll
      for (int i = 0; i < 8; ++i) {
        int r = rb + 8 * i;
        float xv = xs[r][ni];
        s16x8 pk;
#pragma unroll
        for (int j = 0; j < 4; ++j) {
          float z0 = fmaf(xv, wlo[j], blo[j]);
          float z1 = fmaf(xv, whi[j], bhi[j]);
          float e0 = fmaxf(z0, 0.f) + (__expf(fminf(z0, 0.f)) - 1.f);
          float e1 = fmaxf(z1, 0.f) + (__expf(fminf(z1, 0.f)) - 1.f);
          __hip_bfloat16 h0 = __float2bfloat16(e0);
          __hip_bfloat16 h1 = __float2bfloat16(e1);
          pk[j]     = *reinterpret_cast<short*>(&h0);
          pk[j + 4] = *reinterpret_cast<short*>(&h1);
        }
        *reinterpret_cast<s16x8*>(Ab + r * 512 + ((kc << 4) ^ ((r & 7) << 4))) = pk;
      }
    }
    __syncthreads();

    f32x4 acc[4][4];
#pragma unroll
    for (int a = 0; a < 4; ++a)
#pragma unroll
      for (int b = 0; b < 4; ++b) acc[a][b] = (f32x4){0.f, 0.f, 0.f, 0.f};

    for (int kt = 0; kt < 4; ++kt) {
      const ushort* gsrc = w2p + ((size_t)(n * 4 + kt) * 2048) * 8;
#pragma unroll
      for (int ii = 0; ii < 8; ++ii) {
        int chunk = ii * 256 + t;
        __builtin_amdgcn_global_load_lds(
            (const __attribute__((address_space(1))) unsigned int*)(gsrc + chunk * 8),
            (__attribute__((address_space(3))) unsigned int*)(Bb + chunk * 16),
            16, 0, 0);
      }
      __syncthreads();
#pragma unroll
      for (int ks = 0; ks < 2; ++ks) {
        const int kabs = kt * 2 + ks;
        s16x8 af[4], bf[4];
#pragma unroll
        for (int mt = 0; mt < 4; ++mt) {
          int row = mt * 16 + cl;
          int kcA = kabs * 4 + g;
          af[mt] = *reinterpret_cast<const s16x8*>(
              Ab + row * 512 + ((kcA << 4) ^ ((row & 7) << 4)));
        }
#pragma unroll
        for (int ct = 0; ct < 4; ++ct) {
          int c = w * 64 + ct * 16 + cl;
          int kcB = ks * 4 + g;
          bf[ct] = *reinterpret_cast<const s16x8*>(
              Bb + c * 128 + ((kcB << 4) ^ ((c & 7) << 4)));
        }
#pragma unroll
        for (int mt = 0; mt < 4; ++mt)
#pragma unroll
          for (int ct = 0; ct < 4; ++ct)
            acc[mt][ct] = __builtin_amdgcn_mfma_f32_16x16x32_bf16(
                af[mt], bf[ct], acc[mt][ct], 0, 0, 0);
      }
      __syncthreads();
    }

    // ---- epilogue: gate mix, LN over H=256, weighted accumulate ----
    {
      float xv[4][4], rsum[4][4], rsq[4][4];
#pragma unroll
      for (int mt = 0; mt < 4; ++mt)
#pragma unroll
        for (int rg = 0; rg < 4; ++rg) {
          xv[mt][rg] = xs[mt * 16 + g * 4 + rg][ni];
          rsum[mt][rg] = 0.f;
          rsq[mt][rg] = 0.f;
        }
#pragma unroll
      for (int ct = 0; ct < 4; ++ct) {
        int c = w * 64 + ct * 16 + cl;
        float f2b = fc2b[n * 256 + c];
        float sw_ = skw[n * 256 + c], sb_ = skb[n * 256 + c];
        float gw_ = gww[n * 256 + c], gb_ = gwb[n * 256 + c];
#pragma unroll
        for (int mt = 0; mt < 4; ++mt)
#pragma unroll
          for (int rg = 0; rg < 4; ++rg) {
            float hv = acc[mt][ct][rg] + f2b;
            float xr = xv[mt][rg];
            float sk = fmaf(xr, sw_, sb_);
            float zg = fmaf(xr, gw_, gb_);
            float gv = __fdividef(1.f, 1.f + __expf(-zg));
            float p = fmaf(gv, hv - sk, sk);
            acc[mt][ct][rg] = p;
            rsum[mt][rg] += p;
            rsq[mt][rg] = fmaf(p, p, rsq[mt][rg]);
          }
      }
#pragma unroll
      for (int mt = 0; mt < 4; ++mt)
#pragma unroll
        for (int rg = 0; rg < 4; ++rg) {
#pragma unroll
          for (int m = 1; m < 16; m <<= 1) {
            rsum[mt][rg] += __shfl_xor(rsum[mt][rg], m);
            rsq[mt][rg]  += __shfl_xor(rsq[mt][rg], m);
          }
        }
      if (cl == 0) {
#pragma unroll
        for (int mt = 0; mt < 4; ++mt)
#pragma unroll
          for (int rg = 0; rg < 4; ++rg) {
            int row = mt * 16 + g * 4 + rg;
            atomicAdd(&sums[row][0], rsum[mt][rg]);
            atomicAdd(&sums[row][1], rsq[mt][rg]);
          }
      }
      __syncthreads();
      float muv[4][4], rsv[4][4], svv[4][4];
#pragma unroll
      for (int mt = 0; mt < 4; ++mt)
#pragma unroll
        for (int rg = 0; rg < 4; ++rg) {
          int row = mt * 16 + g * 4 + rg;
          float mu = sums[row][0] * (1.f / 256.f);
          float e2 = sums[row][1] * (1.f / 256.f);
          muv[mt][rg] = mu;
          rsv[mt][rg] = rsqrtf(fmaxf(e2 - mu * mu, 0.f) + 1e-5f);
          svv[mt][rg] = ss[row][ni];
        }
#pragma unroll
      for (int ct = 0; ct < 4; ++ct) {
        int c = w * 64 + ct * 16 + cl;
        float gl = lng[n * 256 + c];
        float bl = lnb[n * 256 + c];
#pragma unroll
        for (int mt = 0; mt < 4; ++mt)
#pragma unroll
          for (int rg = 0; rg < 4; ++rg) {
            float p = acc[mt][ct][rg];
            float emb = fmaf((p - muv[mt][rg]) * rsv[mt][rg], gl, bl);
            comb_acc[mt][ct][rg] = fmaf(svv[mt][rg], emb, comb_acc[mt][ct][rg]);
          }
      }
      __syncthreads();
    }
  }

#pragma unroll
  for (int mt = 0; mt < 4; ++mt)
#pragma unroll
    for (int rg = 0; rg < 4; ++rg) {
      int row = b0 + mt * 16 + g * 4 + rg;
#pragma unroll
      for (int ct = 0; ct < 4; ++ct) {
        int c = w * 64 + ct * 16 + cl;
        atomicAdd(&comb[(size_t)row * 256 + c], comb_acc[mt][ct][rg]);
      }
    }
}

// ---------------------------------------------------------------------------
extern "C" void kernel_launch(void* const* d_in, const int* in_sizes, int n_in,
                              void* d_out, int out_size, void* d_ws, size_t ws_size,
                              hipStream_t stream) {
  const float* x   = (const float*)d_in[0];
  const float* f1w = (const float*)d_in[1];
  const float* f1b = (const float*)d_in[2];
  const float* f2w = (const float*)d_in[3];
  const float* f2b = (const float*)d_in[4];
  const float* fsw = (const float*)d_in[5];
  const float* fsb = (const float*)d_in[6];
  const float* fgw = (const float*)d_in[7];
  const float* fgb = (const float*)d_in[8];
  const float* flg = (const float*)d_in[9];
  const float* flb = (const float*)d_in[10];
  const float* g1w = (const float*)d_in[11];
  const float* g1b = (const float*)d_in[12];
  const float* g2w = (const float*)d_in[13];
  const float* g2b = (const float*)d_in[14];
  const float* gsw = (const float*)d_in[15];
  const float* gsb = (const float*)d_in[16];
  const float* ggw = (const float*)d_in[17];
  const float* ggb = (const float*)d_in[18];
  const float* glg = (const float*)d_in[19];
  const float* glb = (const float*)d_in[20];

  float* out  = (float*)d_out;
  float* comb = out;                          // (4096,256)
  float* spw  = out + (size_t)4096 * 256;     // (4096,64)
  ushort* w2p = (ushort*)d_ws;                // 8.4 MB packed bf16 weights

  hipMemsetAsync(comb, 0, (size_t)4096 * 256 * sizeof(float), stream);
  k0_pack<<<2048, 256, 0, stream>>>(g2w, w2p);
  k1_select<<<256, 256, 0, stream>>>(x, f1w, f1b, f2w, f2b, fsw, fsb,
                                     fgw, fgb, flg, flb, spw);
  k2_main<<<512, 256, 0, stream>>>(x, w2p, g1w, g1b, g2b, gsw, gsb,
                                   ggw, ggb, glg, glb, spw, comb);
}